// Round 1
// baseline (1188.595 us; speedup 1.0000x reference)
//
#include <hip/hip_runtime.h>
#include <hip/hip_bf16.h>

// GCN: h1 = relu(Â (x W1) + b1); h2 = relu(Â (h1 W2) + b2);
// out = mean_pool(h2, batch) @ Wlin + blin,  Â = D^-1/2 (A+I) D^-1/2
//
// Strategy: build CSR (by dst) on device each launch, then gather-aggregate
// (one wave per node, lane = feature dim). No float scatter atomics.

#define NDIM 64
#define NGRAPH 64

// ---- degree count: degi[dst[e]] += 1 ----
__global__ void count_k(const int* __restrict__ dst, int* __restrict__ degi, int e) {
    int i = blockIdx.x * blockDim.x + threadIdx.x;
    if (i < e) atomicAdd(&degi[dst[i]], 1);
}

// ---- dinv[v] = rsqrt(indeg+1); also per-graph node counts ----
__global__ void dinv_k(const int* __restrict__ degi, const int* __restrict__ batch,
                       float* __restrict__ dinv, int* __restrict__ cnti, int n) {
    int v = blockIdx.x * blockDim.x + threadIdx.x;
    if (v >= n) return;
    dinv[v] = rsqrtf((float)(degi[v] + 1));
    atomicAdd(&cnti[batch[v]], 1);
}

// ---- CSR region allocation: block-local exclusive scan + 1 atomic/block ----
// (region assignment order across blocks is irrelevant for a sum)
__global__ void alloc_k(const int* __restrict__ degi, int* __restrict__ start,
                        int* __restrict__ cursor, int* __restrict__ total, int n) {
    __shared__ int sdata[256];
    __shared__ int sbase;
    int t = threadIdx.x;
    int v = blockIdx.x * 256 + t;
    int d = (v < n) ? degi[v] : 0;
    sdata[t] = d;
    __syncthreads();
    for (int off = 1; off < 256; off <<= 1) {
        int tmp = (t >= off) ? sdata[t - off] : 0;
        __syncthreads();
        sdata[t] += tmp;
        __syncthreads();
    }
    if (t == 255) sbase = atomicAdd(total, sdata[255]);
    __syncthreads();
    if (v < n) {
        int s = sbase + sdata[t] - d;   // exclusive offset
        start[v] = s;
        cursor[v] = s;
    }
}

// ---- fill CSR: record = (src, norm) ----
__global__ void fill_k(const int* __restrict__ src, const int* __restrict__ dst,
                       const float* __restrict__ dinv, int* __restrict__ cursor,
                       int2* __restrict__ csr, int e) {
    int i = blockIdx.x * blockDim.x + threadIdx.x;
    if (i >= e) return;
    int s = src[i], d = dst[i];
    int pos = atomicAdd(&cursor[d], 1);     // cursor starts at start[d] -> absolute
    int2 rec;
    rec.x = s;
    rec.y = __float_as_int(dinv[s] * dinv[d]);
    csr[pos] = rec;
}

// ---- dense GEMM  C[n,64] = A[n,64] @ W[64,64], 4 rows per 256-thread block ----
__global__ void gemm_k(const float* __restrict__ A, const float* __restrict__ W,
                       float* __restrict__ C, int n) {
    __shared__ float Wl[64 * 64];
    __shared__ float Xl[256];
    int t = threadIdx.x;
#pragma unroll
    for (int i = 0; i < 16; ++i) Wl[t + 256 * i] = W[t + 256 * i];
    long base = (long)blockIdx.x * 256;
    Xl[t] = (base + t < (long)n * NDIM) ? A[base + t] : 0.f;
    __syncthreads();
    int row = t >> 6, col = t & 63;
    float acc = 0.f;
#pragma unroll
    for (int k = 0; k < 64; ++k) acc += Xl[row * 64 + k] * Wl[k * 64 + col];
    int v = blockIdx.x * 4 + row;
    if (v < n) C[(long)v * NDIM + col] = acc;
}

// ---- aggregation: out[v,:] = relu( sum_e norm_e * xw[src_e,:] + dinv[v]^2*xw[v,:] + b ) ----
// one 64-lane wave per node, lane = dim; 4 nodes per 256-thread block
__global__ void agg_k(const float* __restrict__ xw, const float* __restrict__ dinv,
                      const int* __restrict__ start, const int* __restrict__ degi,
                      const int2* __restrict__ csr, const float* __restrict__ bias,
                      float* __restrict__ out, int n) {
    int t = threadIdx.x;
    int lane = t & 63;
    int v = blockIdx.x * 4 + (t >> 6);
    if (v >= n) return;
    int s0 = start[v];
    int d0 = degi[v];
    float acc = 0.f;
    if (d0 > 0) {
        int2 rec = csr[s0];
        for (int i = 1; i < d0; ++i) {
            int2 nxt = csr[s0 + i];                       // prefetch next record
            acc += __int_as_float(rec.y) * xw[(long)rec.x * NDIM + lane];
            rec = nxt;
        }
        acc += __int_as_float(rec.y) * xw[(long)rec.x * NDIM + lane];
    }
    float dv = dinv[v];
    acc += dv * dv * xw[(long)v * NDIM + lane];           // self loop
    acc += bias[lane];
    out[(long)v * NDIM + lane] = fmaxf(acc, 0.f);
}

// ---- mean-pool (batch sorted): register accumulate, flush on graph change ----
#define POOL_TILE 256
__global__ void pool_k(const float* __restrict__ h, const int* __restrict__ batch,
                       float* __restrict__ pooled, int n) {
    int t = threadIdx.x;
    int lane = t & 63;
    int sub = t >> 6;                 // 0..3
    int base = blockIdx.x * POOL_TILE;
    int gcur = -1;
    float acc = 0.f;
    for (int k = 0; k < POOL_TILE / 4; ++k) {
        int v = base + sub + 4 * k;   // monotone per thread -> few graph changes
        if (v < n) {
            int g = batch[v];
            if (g != gcur) {
                if (gcur >= 0) atomicAdd(&pooled[gcur * NDIM + lane], acc);
                gcur = g;
                acc = 0.f;
            }
            acc += h[(long)v * NDIM + lane];
        }
    }
    if (gcur >= 0) atomicAdd(&pooled[gcur * NDIM + lane], acc);
}

// ---- head: out[g,c] = (pooled[g,:]/max(cnt,1)) @ Wlin + blin ----
__global__ void final_k(const float* __restrict__ pooled, const int* __restrict__ cnti,
                        const float* __restrict__ Wlin, const float* __restrict__ blin,
                        float* __restrict__ out, int nclass) {
    int t = blockIdx.x * blockDim.x + threadIdx.x;
    if (t >= NGRAPH * nclass) return;
    int g = t / nclass, c = t % nclass;
    float inv = 1.f / fmaxf((float)cnti[g], 1.f);
    float acc = 0.f;
    for (int j = 0; j < NDIM; ++j) acc += pooled[g * NDIM + j] * Wlin[j * nclass + c];
    out[t] = acc * inv + blin[c];
}

extern "C" void kernel_launch(void* const* d_in, const int* in_sizes, int n_in,
                              void* d_out, int out_size, void* d_ws, size_t ws_size,
                              hipStream_t stream) {
    const float* x     = (const float*)d_in[0];
    const int*   ei    = (const int*)d_in[1];
    const int*   batch = (const int*)d_in[2];
    const float* W1    = (const float*)d_in[3];
    const float* b1    = (const float*)d_in[4];
    const float* W2    = (const float*)d_in[5];
    const float* b2    = (const float*)d_in[6];
    const float* Wlin  = (const float*)d_in[7];
    const float* blin  = (const float*)d_in[8];
    float* out = (float*)d_out;

    const int N = in_sizes[0] / NDIM;        // 100000
    const int E = in_sizes[1] / 2;           // 1600000
    const int NCLASS = in_sizes[7] / NDIM;   // 10
    const int* src = ei;
    const int* dst = ei + E;

    // ---- workspace carve-out (each 256B-aligned) ----
    size_t o = 0;
    char* wsp = (char*)d_ws;
    auto take = [&](size_t nbytes) -> void* {
        void* p = (void*)(wsp + o);
        o += (nbytes + 255) & ~(size_t)255;
        return p;
    };
    int*   degi   = (int*)take((size_t)N * 4);
    int*   total  = (int*)take(4);
    int*   cnti   = (int*)take(NGRAPH * 4);
    float* pooled = (float*)take(NGRAPH * NDIM * 4);
    size_t zero_bytes = o;                    // everything above must start at 0
    int*   start  = (int*)take((size_t)N * 4);
    int*   cursor = (int*)take((size_t)N * 4);
    float* dinv   = (float*)take((size_t)N * 4);
    int2*  csr    = (int2*)take((size_t)E * 8);
    float* xw     = (float*)take((size_t)N * NDIM * 4);
    float* h      = (float*)take((size_t)N * NDIM * 4);
    (void)ws_size;

    hipMemsetAsync(d_ws, 0, zero_bytes, stream);

    int ebl = (E + 255) / 256;
    int nbl = (N + 255) / 256;
    int rbl = (N + 3) / 4;                    // 4 nodes per block (gemm/agg)

    // CSR build
    count_k<<<ebl, 256, 0, stream>>>(dst, degi, E);
    dinv_k<<<nbl, 256, 0, stream>>>(degi, batch, dinv, cnti, N);
    alloc_k<<<nbl, 256, 0, stream>>>(degi, start, cursor, total, N);
    fill_k<<<ebl, 256, 0, stream>>>(src, dst, dinv, cursor, csr, E);

    // layer 1
    gemm_k<<<rbl, 256, 0, stream>>>(x, W1, xw, N);
    agg_k<<<rbl, 256, 0, stream>>>(xw, dinv, start, degi, csr, b1, h, N);
    // layer 2
    gemm_k<<<rbl, 256, 0, stream>>>(h, W2, xw, N);
    agg_k<<<rbl, 256, 0, stream>>>(xw, dinv, start, degi, csr, b2, h, N);

    // pooling + head
    pool_k<<<(N + POOL_TILE - 1) / POOL_TILE, 256, 0, stream>>>(h, batch, pooled, N);
    final_k<<<(NGRAPH * NCLASS + 255) / 256, 256, 0, stream>>>(pooled, cnti, Wlin, blin, out, NCLASS);
}

// Round 2
// 676.543 us; speedup vs baseline: 1.7569x; 1.7569x over previous
//
#include <hip/hip_runtime.h>
#include <hip/hip_bf16.h>

// GCN: h1 = relu(Â (x W1) + b1); h2 = relu(Â (h1 W2) + b2);
// out = mean_pool(h2, batch) @ Wlin + blin,  Â = D^-1/2 (A+I) D^-1/2
//
// CSR-by-dst build on device, then gather-aggregate (one wave per node,
// lane = feature dim). No float scatter atomics.
// R2: per-graph counts via sorted-batch boundary detection (gstart/gend)
//     instead of 100K same-address atomics (was 508 us in dinv_k).

#define NDIM 64
#define NGRAPH 64

// ---- degree count: degi[dst[e]] += 1 ----
__global__ void count_k(const int* __restrict__ dst, int* __restrict__ degi, int e) {
    int i = blockIdx.x * blockDim.x + threadIdx.x;
    if (i < e) atomicAdd(&degi[dst[i]], 1);
}

// ---- dinv[v] = rsqrt(indeg+1); per-graph ranges via sorted-batch boundaries ----
__global__ void dinv_k(const int* __restrict__ degi, const int* __restrict__ batch,
                       float* __restrict__ dinv, int* __restrict__ gstart,
                       int* __restrict__ gend, int n) {
    int v = blockIdx.x * blockDim.x + threadIdx.x;
    if (v >= n) return;
    dinv[v] = rsqrtf((float)(degi[v] + 1));
    int g = batch[v];
    if (v == 0 || batch[v - 1] != g) gstart[g] = v;      // <=64 stores total
    if (v == n - 1 || batch[v + 1] != g) gend[g] = v + 1;
}

// ---- CSR region allocation: block-local exclusive scan + 1 atomic/block ----
// (region assignment order across blocks is irrelevant for a sum)
__global__ void alloc_k(const int* __restrict__ degi, int* __restrict__ start,
                        int* __restrict__ cursor, int* __restrict__ total, int n) {
    __shared__ int sdata[256];
    __shared__ int sbase;
    int t = threadIdx.x;
    int v = blockIdx.x * 256 + t;
    int d = (v < n) ? degi[v] : 0;
    sdata[t] = d;
    __syncthreads();
    for (int off = 1; off < 256; off <<= 1) {
        int tmp = (t >= off) ? sdata[t - off] : 0;
        __syncthreads();
        sdata[t] += tmp;
        __syncthreads();
    }
    if (t == 255) sbase = atomicAdd(total, sdata[255]);
    __syncthreads();
    if (v < n) {
        int s = sbase + sdata[t] - d;   // exclusive offset
        start[v] = s;
        cursor[v] = s;
    }
}

// ---- fill CSR: record = (src, norm) ----
__global__ void fill_k(const int* __restrict__ src, const int* __restrict__ dst,
                       const float* __restrict__ dinv, int* __restrict__ cursor,
                       int2* __restrict__ csr, int e) {
    int i = blockIdx.x * blockDim.x + threadIdx.x;
    if (i >= e) return;
    int s = src[i], d = dst[i];
    int pos = atomicAdd(&cursor[d], 1);     // cursor starts at start[d] -> absolute
    int2 rec;
    rec.x = s;
    rec.y = __float_as_int(dinv[s] * dinv[d]);
    csr[pos] = rec;
}

// ---- dense GEMM  C[n,64] = A[n,64] @ W[64,64], 4 rows per 256-thread block ----
__global__ void gemm_k(const float* __restrict__ A, const float* __restrict__ W,
                       float* __restrict__ C, int n) {
    __shared__ float Wl[64 * 64];
    __shared__ float Xl[256];
    int t = threadIdx.x;
#pragma unroll
    for (int i = 0; i < 16; ++i) Wl[t + 256 * i] = W[t + 256 * i];
    long base = (long)blockIdx.x * 256;
    Xl[t] = (base + t < (long)n * NDIM) ? A[base + t] : 0.f;
    __syncthreads();
    int row = t >> 6, col = t & 63;
    float acc = 0.f;
#pragma unroll
    for (int k = 0; k < 64; ++k) acc += Xl[row * 64 + k] * Wl[k * 64 + col];
    int v = blockIdx.x * 4 + row;
    if (v < n) C[(long)v * NDIM + col] = acc;
}

// ---- aggregation: out[v,:] = relu( sum_e norm_e * xw[src_e,:] + dinv[v]^2*xw[v,:] + b ) ----
// one 64-lane wave per node, lane = dim; 4 nodes per 256-thread block
__global__ void agg_k(const float* __restrict__ xw, const float* __restrict__ dinv,
                      const int* __restrict__ start, const int* __restrict__ degi,
                      const int2* __restrict__ csr, const float* __restrict__ bias,
                      float* __restrict__ out, int n) {
    int t = threadIdx.x;
    int lane = t & 63;
    int v = blockIdx.x * 4 + (t >> 6);
    if (v >= n) return;
    int s0 = start[v];
    int d0 = degi[v];
    float acc = 0.f;
    if (d0 > 0) {
        int2 rec = csr[s0];
        for (int i = 1; i < d0; ++i) {
            int2 nxt = csr[s0 + i];                       // prefetch next record
            acc += __int_as_float(rec.y) * xw[(long)rec.x * NDIM + lane];
            rec = nxt;
        }
        acc += __int_as_float(rec.y) * xw[(long)rec.x * NDIM + lane];
    }
    float dv = dinv[v];
    acc += dv * dv * xw[(long)v * NDIM + lane];           // self loop
    acc += bias[lane];
    out[(long)v * NDIM + lane] = fmaxf(acc, 0.f);
}

// ---- mean-pool (batch sorted): register accumulate, flush on graph change ----
#define POOL_TILE 256
__global__ void pool_k(const float* __restrict__ h, const int* __restrict__ batch,
                       float* __restrict__ pooled, int n) {
    int t = threadIdx.x;
    int lane = t & 63;
    int sub = t >> 6;                 // 0..3
    int base = blockIdx.x * POOL_TILE;
    int gcur = -1;
    float acc = 0.f;
    for (int k = 0; k < POOL_TILE / 4; ++k) {
        int v = base + sub + 4 * k;   // monotone per thread -> few graph changes
        if (v < n) {
            int g = batch[v];
            if (g != gcur) {
                if (gcur >= 0) atomicAdd(&pooled[gcur * NDIM + lane], acc);
                gcur = g;
                acc = 0.f;
            }
            acc += h[(long)v * NDIM + lane];
        }
    }
    if (gcur >= 0) atomicAdd(&pooled[gcur * NDIM + lane], acc);
}

// ---- head: out[g,c] = (pooled[g,:]/max(cnt,1)) @ Wlin + blin ----
__global__ void final_k(const float* __restrict__ pooled, const int* __restrict__ gstart,
                        const int* __restrict__ gend,
                        const float* __restrict__ Wlin, const float* __restrict__ blin,
                        float* __restrict__ out, int nclass) {
    int t = blockIdx.x * blockDim.x + threadIdx.x;
    if (t >= NGRAPH * nclass) return;
    int g = t / nclass, c = t % nclass;
    float cnt = (float)(gend[g] - gstart[g]);
    float inv = 1.f / fmaxf(cnt, 1.f);
    float acc = 0.f;
    for (int j = 0; j < NDIM; ++j) acc += pooled[g * NDIM + j] * Wlin[j * nclass + c];
    out[t] = acc * inv + blin[c];
}

extern "C" void kernel_launch(void* const* d_in, const int* in_sizes, int n_in,
                              void* d_out, int out_size, void* d_ws, size_t ws_size,
                              hipStream_t stream) {
    const float* x     = (const float*)d_in[0];
    const int*   ei    = (const int*)d_in[1];
    const int*   batch = (const int*)d_in[2];
    const float* W1    = (const float*)d_in[3];
    const float* b1    = (const float*)d_in[4];
    const float* W2    = (const float*)d_in[5];
    const float* b2    = (const float*)d_in[6];
    const float* Wlin  = (const float*)d_in[7];
    const float* blin  = (const float*)d_in[8];
    float* out = (float*)d_out;

    const int N = in_sizes[0] / NDIM;        // 100000
    const int E = in_sizes[1] / 2;           // 1600000
    const int NCLASS = in_sizes[7] / NDIM;   // 10
    const int* src = ei;
    const int* dst = ei + E;

    // ---- workspace carve-out (each 256B-aligned) ----
    size_t o = 0;
    char* wsp = (char*)d_ws;
    auto take = [&](size_t nbytes) -> void* {
        void* p = (void*)(wsp + o);
        o += (nbytes + 255) & ~(size_t)255;
        return p;
    };
    int*   degi   = (int*)take((size_t)N * 4);
    int*   total  = (int*)take(4);
    int*   gstart = (int*)take(NGRAPH * 4);
    int*   gend   = (int*)take(NGRAPH * 4);
    float* pooled = (float*)take(NGRAPH * NDIM * 4);
    size_t zero_bytes = o;                    // everything above must start at 0
    int*   start  = (int*)take((size_t)N * 4);
    int*   cursor = (int*)take((size_t)N * 4);
    float* dinv   = (float*)take((size_t)N * 4);
    int2*  csr    = (int2*)take((size_t)E * 8);
    float* xw     = (float*)take((size_t)N * NDIM * 4);
    float* h      = (float*)take((size_t)N * NDIM * 4);
    (void)ws_size;

    hipMemsetAsync(d_ws, 0, zero_bytes, stream);

    int ebl = (E + 255) / 256;
    int nbl = (N + 255) / 256;
    int rbl = (N + 3) / 4;                    // 4 nodes per block (gemm/agg)

    // CSR build
    count_k<<<ebl, 256, 0, stream>>>(dst, degi, E);
    dinv_k<<<nbl, 256, 0, stream>>>(degi, batch, dinv, gstart, gend, N);
    alloc_k<<<nbl, 256, 0, stream>>>(degi, start, cursor, total, N);
    fill_k<<<ebl, 256, 0, stream>>>(src, dst, dinv, cursor, csr, E);

    // layer 1
    gemm_k<<<rbl, 256, 0, stream>>>(x, W1, xw, N);
    agg_k<<<rbl, 256, 0, stream>>>(xw, dinv, start, degi, csr, b1, h, N);
    // layer 2
    gemm_k<<<rbl, 256, 0, stream>>>(h, W2, xw, N);
    agg_k<<<rbl, 256, 0, stream>>>(xw, dinv, start, degi, csr, b2, h, N);

    // pooling + head
    pool_k<<<(N + POOL_TILE - 1) / POOL_TILE, 256, 0, stream>>>(h, batch, pooled, N);
    final_k<<<(NGRAPH * NCLASS + 255) / 256, 256, 0, stream>>>(pooled, gstart, gend, Wlin, blin, out, NCLASS);
}

// Round 4
// 545.760 us; speedup vs baseline: 2.1779x; 1.2396x over previous
//
#include <hip/hip_runtime.h>
#include <hip/hip_bf16.h>

// GCN: h1 = relu(Â (x W1) + b1); h2 = relu(Â (h1 W2) + b2);
// out = mean_pool(h2, batch) @ Wlin + blin,  Â = D^-1/2 (A+I) D^-1/2
//
// CSR-by-dst build on device, then gather-aggregate (one wave per node,
// lane = feature dim). No float scatter atomics.
// R2: per-graph counts via sorted-batch boundaries (was 508 us of atomics).
// R3: norm folded into gemm epilogue (xws = dinv*xw) -> CSR record is 4 B
//     (src only); agg gather loop unrolled x4 for 4 outstanding row gathers.
// R4: resubmit of R3 (GPU acquisition timeout — kernel never ran).

#define NDIM 64
#define NGRAPH 64

// ---- degree count: degi[dst[e]] += 1 ----
__global__ void count_k(const int* __restrict__ dst, int* __restrict__ degi, int e) {
    int i = blockIdx.x * blockDim.x + threadIdx.x;
    if (i < e) atomicAdd(&degi[dst[i]], 1);
}

// ---- fused: dinv = rsqrt(deg+1), graph ranges, CSR region alloc ----
__global__ void alloc_k(const int* __restrict__ degi, const int* __restrict__ batch,
                        float* __restrict__ dinv, int* __restrict__ gstart,
                        int* __restrict__ gend, int* __restrict__ start,
                        int* __restrict__ cursor, int* __restrict__ total, int n) {
    __shared__ int sdata[256];
    __shared__ int sbase;
    int t = threadIdx.x;
    int v = blockIdx.x * 256 + t;
    int d = 0;
    if (v < n) {
        d = degi[v];
        dinv[v] = rsqrtf((float)(d + 1));
        int g = batch[v];
        if (v == 0 || batch[v - 1] != g) gstart[g] = v;      // <=64 stores total
        if (v == n - 1 || batch[v + 1] != g) gend[g] = v + 1;
    }
    sdata[t] = d;
    __syncthreads();
    for (int off = 1; off < 256; off <<= 1) {
        int tmp = (t >= off) ? sdata[t - off] : 0;
        __syncthreads();
        sdata[t] += tmp;
        __syncthreads();
    }
    if (t == 255) sbase = atomicAdd(total, sdata[255]);
    __syncthreads();
    if (v < n) {
        int s = sbase + sdata[t] - d;   // exclusive offset
        start[v] = s;
        cursor[v] = s;
    }
}

// ---- fill CSR: record = src index only (norm folded into xws) ----
__global__ void fill_k(const int* __restrict__ src, const int* __restrict__ dst,
                       int* __restrict__ cursor, int* __restrict__ csr, int e) {
    int i = blockIdx.x * blockDim.x + threadIdx.x;
    if (i >= e) return;
    int s = src[i], d = dst[i];
    int pos = atomicAdd(&cursor[d], 1);     // cursor starts at start[d] -> absolute
    csr[pos] = s;
}

// ---- dense GEMM  C[n,64] = scale[row] * (A[n,64] @ W[64,64]) ----
// 4 rows per 256-thread block
__global__ void gemm_k(const float* __restrict__ A, const float* __restrict__ W,
                       const float* __restrict__ scale, float* __restrict__ C, int n) {
    __shared__ float Wl[64 * 64];
    __shared__ float Xl[256];
    int t = threadIdx.x;
#pragma unroll
    for (int i = 0; i < 16; ++i) Wl[t + 256 * i] = W[t + 256 * i];
    long base = (long)blockIdx.x * 256;
    Xl[t] = (base + t < (long)n * NDIM) ? A[base + t] : 0.f;
    __syncthreads();
    int row = t >> 6, col = t & 63;
    float acc = 0.f;
    const float4* Xv = (const float4*)&Xl[row * 64];
#pragma unroll
    for (int k4 = 0; k4 < 16; ++k4) {
        float4 xv = Xv[k4];
        acc += xv.x * Wl[(4 * k4 + 0) * 64 + col];
        acc += xv.y * Wl[(4 * k4 + 1) * 64 + col];
        acc += xv.z * Wl[(4 * k4 + 2) * 64 + col];
        acc += xv.w * Wl[(4 * k4 + 3) * 64 + col];
    }
    int v = blockIdx.x * 4 + row;
    if (v < n) C[(long)v * NDIM + col] = scale[v] * acc;
}

// ---- aggregation: out[v,:] = relu( dinv[v]*(sum_e xws[src_e,:] + xws[v,:]) + b ) ----
// one 64-lane wave per node, lane = dim; unrolled x4 -> 4 gathers in flight
__global__ void agg_k(const float* __restrict__ xws, const float* __restrict__ dinv,
                      const int* __restrict__ start, const int* __restrict__ degi,
                      const int* __restrict__ csr, const float* __restrict__ bias,
                      float* __restrict__ out, int n) {
    int t = threadIdx.x;
    int lane = t & 63;
    int v = blockIdx.x * 4 + (t >> 6);
    if (v >= n) return;
    int s0 = start[v];
    int d0 = degi[v];
    float a0 = 0.f, a1 = 0.f, a2 = 0.f, a3 = 0.f;
    int i = 0;
    for (; i + 4 <= d0; i += 4) {
        int j0 = csr[s0 + i + 0];
        int j1 = csr[s0 + i + 1];
        int j2 = csr[s0 + i + 2];
        int j3 = csr[s0 + i + 3];
        float x0 = xws[(long)j0 * NDIM + lane];
        float x1 = xws[(long)j1 * NDIM + lane];
        float x2 = xws[(long)j2 * NDIM + lane];
        float x3 = xws[(long)j3 * NDIM + lane];
        a0 += x0; a1 += x1; a2 += x2; a3 += x3;
    }
    for (; i < d0; ++i) a0 += xws[(long)csr[s0 + i] * NDIM + lane];
    float acc = (a0 + a1) + (a2 + a3);
    acc += xws[(long)v * NDIM + lane];          // self loop (xws already has one dinv)
    acc = acc * dinv[v] + bias[lane];
    out[(long)v * NDIM + lane] = fmaxf(acc, 0.f);
}

// ---- mean-pool (batch sorted): register accumulate, flush on graph change ----
#define POOL_TILE 256
__global__ void pool_k(const float* __restrict__ h, const int* __restrict__ batch,
                       float* __restrict__ pooled, int n) {
    int t = threadIdx.x;
    int lane = t & 63;
    int sub = t >> 6;                 // 0..3
    int base = blockIdx.x * POOL_TILE;
    int gcur = -1;
    float acc = 0.f;
    for (int k = 0; k < POOL_TILE / 4; ++k) {
        int v = base + sub + 4 * k;   // monotone per thread -> few graph changes
        if (v < n) {
            int g = batch[v];
            if (g != gcur) {
                if (gcur >= 0) atomicAdd(&pooled[gcur * NDIM + lane], acc);
                gcur = g;
                acc = 0.f;
            }
            acc += h[(long)v * NDIM + lane];
        }
    }
    if (gcur >= 0) atomicAdd(&pooled[gcur * NDIM + lane], acc);
}

// ---- head: out[g,c] = (pooled[g,:]/max(cnt,1)) @ Wlin + blin ----
__global__ void final_k(const float* __restrict__ pooled, const int* __restrict__ gstart,
                        const int* __restrict__ gend,
                        const float* __restrict__ Wlin, const float* __restrict__ blin,
                        float* __restrict__ out, int nclass) {
    int t = blockIdx.x * blockDim.x + threadIdx.x;
    if (t >= NGRAPH * nclass) return;
    int g = t / nclass, c = t % nclass;
    float cnt = (float)(gend[g] - gstart[g]);
    float inv = 1.f / fmaxf(cnt, 1.f);
    float acc = 0.f;
    for (int j = 0; j < NDIM; ++j) acc += pooled[g * NDIM + j] * Wlin[j * nclass + c];
    out[t] = acc * inv + blin[c];
}

extern "C" void kernel_launch(void* const* d_in, const int* in_sizes, int n_in,
                              void* d_out, int out_size, void* d_ws, size_t ws_size,
                              hipStream_t stream) {
    const float* x     = (const float*)d_in[0];
    const int*   ei    = (const int*)d_in[1];
    const int*   batch = (const int*)d_in[2];
    const float* W1    = (const float*)d_in[3];
    const float* b1    = (const float*)d_in[4];
    const float* W2    = (const float*)d_in[5];
    const float* b2    = (const float*)d_in[6];
    const float* Wlin  = (const float*)d_in[7];
    const float* blin  = (const float*)d_in[8];
    float* out = (float*)d_out;

    const int N = in_sizes[0] / NDIM;        // 100000
    const int E = in_sizes[1] / 2;           // 1600000
    const int NCLASS = in_sizes[7] / NDIM;   // 10
    const int* src = ei;
    const int* dst = ei + E;

    // ---- workspace carve-out (each 256B-aligned) ----
    size_t o = 0;
    char* wsp = (char*)d_ws;
    auto take = [&](size_t nbytes) -> void* {
        void* p = (void*)(wsp + o);
        o += (nbytes + 255) & ~(size_t)255;
        return p;
    };
    int*   degi   = (int*)take((size_t)N * 4);
    int*   total  = (int*)take(4);
    int*   gstart = (int*)take(NGRAPH * 4);
    int*   gend   = (int*)take(NGRAPH * 4);
    float* pooled = (float*)take(NGRAPH * NDIM * 4);
    size_t zero_bytes = o;                    // everything above must start at 0
    int*   start  = (int*)take((size_t)N * 4);
    int*   cursor = (int*)take((size_t)N * 4);
    float* dinv   = (float*)take((size_t)N * 4);
    int*   csr    = (int*)take((size_t)E * 4);
    float* xws    = (float*)take((size_t)N * NDIM * 4);
    float* h      = (float*)take((size_t)N * NDIM * 4);
    (void)ws_size;

    hipMemsetAsync(d_ws, 0, zero_bytes, stream);

    int ebl = (E + 255) / 256;
    int nbl = (N + 255) / 256;
    int rbl = (N + 3) / 4;                    // 4 nodes per block (gemm/agg)

    // CSR build
    count_k<<<ebl, 256, 0, stream>>>(dst, degi, E);
    alloc_k<<<nbl, 256, 0, stream>>>(degi, batch, dinv, gstart, gend, start, cursor, total, N);
    fill_k<<<ebl, 256, 0, stream>>>(src, dst, cursor, csr, E);

    // layer 1
    gemm_k<<<rbl, 256, 0, stream>>>(x, W1, dinv, xws, N);
    agg_k<<<rbl, 256, 0, stream>>>(xws, dinv, start, degi, csr, b1, h, N);
    // layer 2
    gemm_k<<<rbl, 256, 0, stream>>>(h, W2, dinv, xws, N);
    agg_k<<<rbl, 256, 0, stream>>>(xws, dinv, start, degi, csr, b2, h, N);

    // pooling + head
    pool_k<<<(N + POOL_TILE - 1) / POOL_TILE, 256, 0, stream>>>(h, batch, pooled, N);
    final_k<<<(NGRAPH * NCLASS + 255) / 256, 256, 0, stream>>>(pooled, gstart, gend, Wlin, blin, out, NCLASS);
}